// Round 1
// baseline (309.053 us; speedup 1.0000x reference)
//
#include <hip/hip_runtime.h>
#include <math.h>

#define NT 16384
#define D 4096
#define NE 128
#define INV_T (1.0f/0.07f)
#define CEPS 1e-4f

// ---------------- kernel 1: normalize gate weights (rows of wg) ----------------
__global__ __launch_bounds__(256) void k_norm_wg(const float* __restrict__ wg,
                                                 float* __restrict__ wgn) {
    int e = blockIdx.x;
    const float4* row = (const float4*)(wg + (size_t)e * D);
    float4* orow = (float4*)(wgn + (size_t)e * D);
    float ss = 0.f;
    float4 v[4];
    #pragma unroll
    for (int c = 0; c < 4; c++) {
        v[c] = row[threadIdx.x + 256 * c];
        ss += v[c].x * v[c].x + v[c].y * v[c].y + v[c].z * v[c].z + v[c].w * v[c].w;
    }
    __shared__ float red[4];
    #pragma unroll
    for (int o = 32; o > 0; o >>= 1) ss += __shfl_xor(ss, o, 64);
    if ((threadIdx.x & 63) == 0) red[threadIdx.x >> 6] = ss;
    __syncthreads();
    float den = fmaxf(sqrtf(red[0] + red[1] + red[2] + red[3]), CEPS);
    #pragma unroll
    for (int c = 0; c < 4; c++) {
        float4 o4;
        o4.x = v[c].x / den; o4.y = v[c].y / den;
        o4.z = v[c].z / den; o4.w = v[c].w / den;
        orow[threadIdx.x + 256 * c] = o4;
    }
}

// ---------------- kernel 2: fused cosine-logits GEMM + argmax + softmax sums ---
// block: 256 threads, 32 tokens x 128 experts. grid: 512 blocks.
__global__ __launch_bounds__(256) void k_main(const float* __restrict__ x,
                                              const float* __restrict__ wgn,
                                              int* __restrict__ tte,
                                              float* __restrict__ me_part) {
    __shared__ float xs[32][32];       // [token][k]
    __shared__ float wsm[32][128];     // [k][expert]  (k-major for conflict-free reads)
    __shared__ float norm2[32];
    __shared__ float metile[8][128];

    const int tid = threadIdx.x;
    const int t0 = blockIdx.x * 32;

    // staging roles
    const int xr  = tid >> 3;          // token row 0..31
    const int xkc = (tid & 7) * 4;     // k offset (float4)
    const int we  = tid & 127;         // expert row
    const int wkh = (tid >> 7) * 16;   // k half 0/16

    // compute roles: 4 tokens x 4 experts per thread
    const int tg = tid >> 5;           // 0..7
    const int eg = tid & 31;           // 0..31
    const int e0 = eg * 4;

    const float* xrow = x + (size_t)(t0 + xr) * D + xkc;
    const float* wrow = wgn + (size_t)we * D + wkh;

    float acc[4][4];
    #pragma unroll
    for (int i = 0; i < 4; i++)
        #pragma unroll
        for (int j = 0; j < 4; j++) acc[i][j] = 0.f;
    float ssq = 0.f;

    // prefetch chunk 0
    float4 xv = *(const float4*)(xrow);
    float4 wv4[4];
    #pragma unroll
    for (int c = 0; c < 4; c++) wv4[c] = *(const float4*)(wrow + c * 4);

    for (int k0 = 0; k0 < D; k0 += 32) {
        // stage current chunk (and accumulate ||x|| on the fly)
        ssq += xv.x * xv.x + xv.y * xv.y + xv.z * xv.z + xv.w * xv.w;
        *(float4*)&xs[xr][xkc] = xv;
        #pragma unroll
        for (int c = 0; c < 4; c++) {
            int kk = wkh + c * 4;
            wsm[kk + 0][we] = wv4[c].x;
            wsm[kk + 1][we] = wv4[c].y;
            wsm[kk + 2][we] = wv4[c].z;
            wsm[kk + 3][we] = wv4[c].w;
        }
        __syncthreads();
        // prefetch next chunk while computing this one
        if (k0 + 32 < D) {
            xv = *(const float4*)(xrow + k0 + 32);
            #pragma unroll
            for (int c = 0; c < 4; c++) wv4[c] = *(const float4*)(wrow + k0 + 32 + c * 4);
        }
        // compute 4x4 outer products over this k-chunk
        #pragma unroll
        for (int kk = 0; kk < 32; kk += 4) {
            float xk[4][4];
            #pragma unroll
            for (int i = 0; i < 4; i++) {
                float4 xa = *(const float4*)&xs[tg * 4 + i][kk];
                xk[i][0] = xa.x; xk[i][1] = xa.y; xk[i][2] = xa.z; xk[i][3] = xa.w;
            }
            #pragma unroll
            for (int m = 0; m < 4; m++) {
                float4 wv = *(const float4*)&wsm[kk + m][e0];
                #pragma unroll
                for (int i = 0; i < 4; i++) {
                    acc[i][0] = fmaf(xk[i][m], wv.x, acc[i][0]);
                    acc[i][1] = fmaf(xk[i][m], wv.y, acc[i][1]);
                    acc[i][2] = fmaf(xk[i][m], wv.z, acc[i][2]);
                    acc[i][3] = fmaf(xk[i][m], wv.w, acc[i][3]);
                }
            }
        }
        __syncthreads();
    }

    // finish per-token x norms (reduce over 8 k-slice lanes)
    ssq += __shfl_xor(ssq, 1, 64);
    ssq += __shfl_xor(ssq, 2, 64);
    ssq += __shfl_xor(ssq, 4, 64);
    if ((tid & 7) == 0) norm2[xr] = ssq;
    __syncthreads();

    float gpart[4] = {0.f, 0.f, 0.f, 0.f};
    #pragma unroll
    for (int i = 0; i < 4; i++) {
        int t = tg * 4 + i;
        float scl = 1.0f / fmaxf(sqrtf(norm2[t]), CEPS);
        float L0 = acc[i][0] * scl, L1 = acc[i][1] * scl;
        float L2 = acc[i][2] * scl, L3 = acc[i][3] * scl;
        // local argmax (first-index tie-break)
        float m = L0; int a = e0;
        if (L1 > m) { m = L1; a = e0 + 1; }
        if (L2 > m) { m = L2; a = e0 + 2; }
        if (L3 > m) { m = L3; a = e0 + 3; }
        // reduce over the 32 lanes covering all 128 experts
        #pragma unroll
        for (int o = 1; o < 32; o <<= 1) {
            float m2 = __shfl_xor(m, o, 64);
            int a2 = __shfl_xor(a, o, 64);
            if (m2 > m || (m2 == m && a2 < a)) { m = m2; a = a2; }
        }
        // softmax(logits / 0.07) pieces
        float ex0 = __expf((L0 - m) * INV_T);
        float ex1 = __expf((L1 - m) * INV_T);
        float ex2 = __expf((L2 - m) * INV_T);
        float ex3 = __expf((L3 - m) * INV_T);
        float s = ex0 + ex1 + ex2 + ex3;
        #pragma unroll
        for (int o = 1; o < 32; o <<= 1) s += __shfl_xor(s, o, 64);
        float inv = 1.0f / s;
        gpart[0] += ex0 * inv; gpart[1] += ex1 * inv;
        gpart[2] += ex2 * inv; gpart[3] += ex3 * inv;
        if (eg == 0) tte[t0 + t] = a;
    }
    *(float4*)&metile[tg][e0] = make_float4(gpart[0], gpart[1], gpart[2], gpart[3]);
    __syncthreads();
    if (tid < 128) {
        float s = 0.f;
        #pragma unroll
        for (int g = 0; g < 8; g++) s += metile[g][tid];
        me_part[(size_t)blockIdx.x * 128 + tid] = s;
    }
}

// ---------------- kernel 3: per-chunk expert histograms -----------------------
__global__ __launch_bounds__(256) void k_hist(const int* __restrict__ tte,
                                              int* __restrict__ hist) {
    __shared__ int h[128];
    int tid = threadIdx.x;
    if (tid < 128) h[tid] = 0;
    __syncthreads();
    int e = tte[blockIdx.x * 256 + tid];
    atomicAdd(&h[e], 1);
    __syncthreads();
    if (tid < 128) hist[blockIdx.x * 128 + tid] = h[tid];
}

// ---------------- kernel 4: scans + l_aux + splits ----------------------------
__global__ __launch_bounds__(128) void k_scan(const int* __restrict__ hist,
                                              const float* __restrict__ me_part,
                                              int* __restrict__ posbase,
                                              float* __restrict__ out) {
    __shared__ int total[128];
    __shared__ float me[128];
    int e = threadIdx.x;
    // totals per expert
    int run = 0;
    #pragma unroll 8
    for (int c = 0; c < 64; c++) run += hist[c * 128 + e];
    total[e] = run;
    __syncthreads();
    // exclusive scan over experts (each thread sums predecessors from LDS)
    int off = 0;
    for (int i = 0; i < e; i++) off += total[i];
    // chunk-wise exclusive prefix per expert -> absolute position bases
    int p = off;
    for (int c = 0; c < 64; c++) {
        posbase[c * 128 + e] = p;
        p += hist[c * 128 + e];
    }
    // reduce me over the 512 main-kernel blocks (deterministic)
    float s = 0.f;
    #pragma unroll 8
    for (int b = 0; b < 512; b++) s += me_part[b * 128 + e];
    me[e] = s;
    __syncthreads();
    if (e == 0) {
        float acc = 0.f;
        for (int i = 0; i < 128; i++)
            acc += me[i] * ((float)total[i] * (1.0f / 16384.0f) + 1e-6f);
        out[0] = acc * 128.0f;   // l_aux
    }
    out[1 + NT + e]      = (float)total[e];   // input_splits
    out[1 + NT + NE + e] = (float)total[e];   // output_splits
}

// ---------------- kernel 5: stable placement (counting sort) ------------------
__global__ __launch_bounds__(256) void k_place(const int* __restrict__ tte,
                                               const int* __restrict__ posbase,
                                               float* __restrict__ out) {
    __shared__ int arr[256];
    int tid = threadIdx.x;
    int c = blockIdx.x;
    int t = c * 256 + tid;
    int e = tte[t];
    arr[tid] = e;
    __syncthreads();
    int rank = 0;
    for (int j = 0; j < tid; j++) rank += (arr[j] == e) ? 1 : 0;
    int pos = posbase[c * 128 + e] + rank;
    out[1 + pos] = (float)t;   // sort_by_expert[pos] = token index
}

// ---------------- launcher ----------------------------------------------------
extern "C" void kernel_launch(void* const* d_in, const int* in_sizes, int n_in,
                              void* d_out, int out_size, void* d_ws, size_t ws_size,
                              hipStream_t stream) {
    const float* x  = (const float*)d_in[0];
    const float* wg = (const float*)d_in[1];
    // d_in[2] = gating_t: monotonic under sigmoid/temp -> unused for argmax
    float* out = (float*)d_out;

    // workspace carve-up
    float* wgn     = (float*)d_ws;                    // 128*4096 f32 = 2 MB
    int*   tte     = (int*)(wgn + (size_t)NE * D);    // 16384 i32
    float* me_part = (float*)(tte + NT);              // 512*128 f32
    int*   hist    = (int*)(me_part + 512 * NE);      // 64*128 i32
    int*   posbase = hist + 64 * NE;                  // 64*128 i32

    k_norm_wg<<<NE, 256, 0, stream>>>(wg, wgn);
    k_main<<<NT / 32, 256, 0, stream>>>(x, wgn, tte, me_part);
    k_hist<<<NT / 256, 256, 0, stream>>>(tte, hist);
    k_scan<<<1, 128, 0, stream>>>(hist, me_part, posbase, out);
    k_place<<<NT / 256, 256, 0, stream>>>(tte, posbase, out);
}